// Round 13
// baseline (104.952 us; speedup 1.0000x reference)
//
#include <hip/hip_runtime.h>
#include <cstdint>

#define P 7
#define PP 49
#define IMG 64
#define PIX 4096
#define XSTR 72    // LDS row stride: 288B, 16B-aligned rows -> b128 merging
#define XROWS 28   // xs tile rows: x rows q*16-6 .. q*16+21
#define MROWS 22   // ms tile rows: maps1 rows q*16-3 .. q*16+18

// fence: only ALU/VALU may cross -> DS reads AND scalar (SMEM) loads stay
// pinned to their region (bounded liveness + prefetch placement holds)
#define FENCE __builtin_amdgcn_sched_barrier(0x3);

// ---- two 10-float window row sets (named scalars; alternate per row) ----
#define DECLRQ \
    float r0,r1,r2,r3,r4,r5,r6,r7,r8,r9; \
    float q0,q1,q2,q3,q4,q5,q6,q7,q8,q9;

#define LDR(BP) { const float* _p=(BP); r0=_p[0];r1=_p[1];r2=_p[2];r3=_p[3];r4=_p[4];r5=_p[5];r6=_p[6];r7=_p[7];r8=_p[8];r9=_p[9]; }
#define LDQ(BP) { const float* _p=(BP); q0=_p[0];q1=_p[1];q2=_p[2];q3=_p[3];q4=_p[4];q5=_p[5];q6=_p[6];q7=_p[7];q8=_p[8];q9=_p[9]; }

// per-row sums: px p uses cols p..p+6, j-ascending (bit-identical to r9-r12)
#define SUMR \
    s0+=r0; s1+=r1; s2+=r2; s3+=r3; \
    s0+=r1; s1+=r2; s2+=r3; s3+=r4; \
    s0+=r2; s1+=r3; s2+=r4; s3+=r5; \
    s0+=r3; s1+=r4; s2+=r5; s3+=r6; \
    s0+=r4; s1+=r5; s2+=r6; s3+=r7; \
    s0+=r5; s1+=r6; s2+=r7; s3+=r8; \
    s0+=r6; s1+=r7; s2+=r8; s3+=r9;
#define SUMQ \
    s0+=q0; s1+=q1; s2+=q2; s3+=q3; \
    s0+=q1; s1+=q2; s2+=q3; s3+=q4; \
    s0+=q2; s1+=q3; s2+=q4; s3+=q5; \
    s0+=q3; s1+=q4; s2+=q5; s3+=q6; \
    s0+=q4; s1+=q5; s2+=q6; s3+=q7; \
    s0+=q5; s1+=q6; s2+=q7; s3+=q8; \
    s0+=q6; s1+=q7; s2+=q8; s3+=q9;

// pipelined sum pass: load row i+1 while summing row i (rows ascending)
#define SUMPASS(B) \
    LDR((B)+0*XSTR) FENCE \
    LDQ((B)+1*XSTR) FENCE \
    SUMR FENCE \
    LDR((B)+2*XSTR) FENCE \
    SUMQ FENCE \
    LDQ((B)+3*XSTR) FENCE \
    SUMR FENCE \
    LDR((B)+4*XSTR) FENCE \
    SUMQ FENCE \
    LDQ((B)+5*XSTR) FENCE \
    SUMR FENCE \
    LDR((B)+6*XSTR) FENCE \
    SUMQ FENCE \
    SUMR

// ---- stage 1 tap: weight W is an SGPR-resident scalar ----
#define S1C(W,RA,RB,RC,RD) \
    a0=fmaf(W,(RA)-mu0,a0); a1=fmaf(W,(RB)-mu1,a1); \
    a2=fmaf(W,(RC)-mu2,a2); a3=fmaf(W,(RD)-mu3,a3); FENCE

// ---- stage 2 tap: 8 SGPR weights, 4 px; order identical to r12 ----
#define S2C(w0_,w1_,w2_,w3_,w4_,w5_,w6_,w7_,RA,RB,RC,RD) { \
    const float t0=(RA)-mu0, t1=(RB)-mu1, t2=(RC)-mu2, t3=(RD)-mu3; \
    a0=fmaf(w0_,t0,a0); b0=fmaf(w0_,t1,b0); c0=fmaf(w0_,t2,c0); d0=fmaf(w0_,t3,d0); \
    a1=fmaf(w1_,t0,a1); b1=fmaf(w1_,t1,b1); c1=fmaf(w1_,t2,c1); d1=fmaf(w1_,t3,d1); \
    a2=fmaf(w2_,t0,a2); b2=fmaf(w2_,t1,b2); c2=fmaf(w2_,t2,c2); d2=fmaf(w2_,t3,d2); \
    a3=fmaf(w3_,t0,a3); b3=fmaf(w3_,t1,b3); c3=fmaf(w3_,t2,c3); d3=fmaf(w3_,t3,d3); \
    a4=fmaf(w4_,t0,a4); b4=fmaf(w4_,t1,b4); c4=fmaf(w4_,t2,c4); d4=fmaf(w4_,t3,d4); \
    a5=fmaf(w5_,t0,a5); b5=fmaf(w5_,t1,b5); c5=fmaf(w5_,t2,c5); d5=fmaf(w5_,t3,d5); \
    a6=fmaf(w6_,t0,a6); b6=fmaf(w6_,t1,b6); c6=fmaf(w6_,t2,c6); d6=fmaf(w6_,t3,d6); \
    a7=fmaf(w7_,t0,a7); b7=fmaf(w7_,t1,b7); c7=fmaf(w7_,t2,c7); d7=fmaf(w7_,t3,d7); } FENCE

// prefetch one 4-tap weight group (32 contiguous floats) into SGPR set S
#define PFG32(S,G) \
    S##0 =W2[(G)*32+0];  S##1 =W2[(G)*32+1];  S##2 =W2[(G)*32+2];  S##3 =W2[(G)*32+3]; \
    S##4 =W2[(G)*32+4];  S##5 =W2[(G)*32+5];  S##6 =W2[(G)*32+6];  S##7 =W2[(G)*32+7]; \
    S##8 =W2[(G)*32+8];  S##9 =W2[(G)*32+9];  S##10=W2[(G)*32+10]; S##11=W2[(G)*32+11]; \
    S##12=W2[(G)*32+12]; S##13=W2[(G)*32+13]; S##14=W2[(G)*32+14]; S##15=W2[(G)*32+15]; \
    S##16=W2[(G)*32+16]; S##17=W2[(G)*32+17]; S##18=W2[(G)*32+18]; S##19=W2[(G)*32+19]; \
    S##20=W2[(G)*32+20]; S##21=W2[(G)*32+21]; S##22=W2[(G)*32+22]; S##23=W2[(G)*32+23]; \
    S##24=W2[(G)*32+24]; S##25=W2[(G)*32+25]; S##26=W2[(G)*32+26]; S##27=W2[(G)*32+27]; \
    S##28=W2[(G)*32+28]; S##29=W2[(G)*32+29]; S##30=W2[(G)*32+30]; S##31=W2[(G)*32+31];
#define PFG8(S,G) \
    S##0 =W2[(G)*32+0];  S##1 =W2[(G)*32+1];  S##2 =W2[(G)*32+2];  S##3 =W2[(G)*32+3]; \
    S##4 =W2[(G)*32+4];  S##5 =W2[(G)*32+5];  S##6 =W2[(G)*32+6];  S##7 =W2[(G)*32+7];

// ---------------------------------------------------------------------------
// One block per (channel, row-quarter): 2048 blocks x 256 threads.
// r12 structure; change: weights moved OFF the DS pipe into SGPRs via
// uniform scalar loads (stage-1: all 49 preloaded; stage-2: 2x32 double
// buffer prefetched one 4-tap group ahead). DS per strip: 140 -> 42 instrs.
// Per-pixel fmaf sequence unchanged -> bit-identical (absmax 0 since r9).
// ---------------------------------------------------------------------------
__global__ __launch_bounds__(256, 4) void stage_kernel(
    const float* __restrict__ x,    // [64][64][64]
    const float* __restrict__ W1,   // [49][8]
    const float* __restrict__ W2,   // [49][8]
    uint8_t* __restrict__ codes)    // [512][4096]
{
    __shared__ __align__(16) float xs[XROWS * XSTR];
    __shared__ __align__(16) float ms[MROWS * XSTR];

    const int b    = blockIdx.x;
    const int ch   = b >> 2;
    const int q16  = (b & 3) * 16;
    const int l    = ch >> 6;
    const int img  = ch & 63;
    const int tid  = threadIdx.x;

    // zero ms (stage-2 SAME padding: pad cols + out-of-image rows stay 0)
    #pragma unroll 1
    for (int i = tid; i < MROWS * XSTR; i += 256) ms[i] = 0.f;

    // load xs zero-padded (xs col c <-> x col c-3; xs row r <-> x row q16-6+r)
    const float* xb = x + (size_t)img * PIX;
    #pragma unroll 1
    for (int idx = tid; idx < XROWS * XSTR; idx += 256) {
        int r  = idx / XSTR, c = idx - r * XSTR;
        int gr = q16 - 6 + r, gc = c - 3;
        float v = 0.f;
        if (gr >= 0 && gr < IMG && gc >= 0 && gc < IMG)
            v = xb[gr * IMG + gc];
        xs[idx] = v;
    }
    __syncthreads();

    // ---- stage-1 weights: 49 uniform scalar loads -> SGPRs (one-time) ----
    const float u0 =W1[0*8+l],  u1 =W1[1*8+l],  u2 =W1[2*8+l],  u3 =W1[3*8+l];
    const float u4 =W1[4*8+l],  u5 =W1[5*8+l],  u6 =W1[6*8+l],  u7 =W1[7*8+l];
    const float u8 =W1[8*8+l],  u9 =W1[9*8+l],  u10=W1[10*8+l], u11=W1[11*8+l];
    const float u12=W1[12*8+l], u13=W1[13*8+l], u14=W1[14*8+l], u15=W1[15*8+l];
    const float u16=W1[16*8+l], u17=W1[17*8+l], u18=W1[18*8+l], u19=W1[19*8+l];
    const float u20=W1[20*8+l], u21=W1[21*8+l], u22=W1[22*8+l], u23=W1[23*8+l];
    const float u24=W1[24*8+l], u25=W1[25*8+l], u26=W1[26*8+l], u27=W1[27*8+l];
    const float u28=W1[28*8+l], u29=W1[29*8+l], u30=W1[30*8+l], u31=W1[31*8+l];
    const float u32=W1[32*8+l], u33=W1[33*8+l], u34=W1[34*8+l], u35=W1[35*8+l];
    const float u36=W1[36*8+l], u37=W1[37*8+l], u38=W1[38*8+l], u39=W1[39*8+l];
    const float u40=W1[40*8+l], u41=W1[41*8+l], u42=W1[42*8+l], u43=W1[43*8+l];
    const float u44=W1[44*8+l], u45=W1[45*8+l], u46=W1[46*8+l], u47=W1[47*8+l];
    const float u48=W1[48*8+l];

    // ---- stage 1: 22 ms-rows x 16 col-strips = 352 strips (4 px each) ----
    #pragma unroll 1
    for (int it = 0; it < 2; ++it) {
        int s = tid + it * 256;
        if (s < MROWS * 16) {
            const int row = s >> 4;           // ms row 0..21
            const int cs4 = (s & 15) * 4;     // pixel col 0..60
            const float* bp = &xs[row * XSTR + cs4];
            DECLRQ
            float s0 = 0.f, s1 = 0.f, s2 = 0.f, s3 = 0.f;
            SUMPASS(bp)
            const float mu0 = s0 / 49.0f, mu1 = s1 / 49.0f;
            const float mu2 = s2 / 49.0f, mu3 = s3 / 49.0f;
            float a0 = 0.f, a1 = 0.f, a2 = 0.f, a3 = 0.f;
            LDR(bp + 0*XSTR) FENCE
            LDQ(bp + 1*XSTR)
            S1C(u0, r0,r1,r2,r3) S1C(u1, r1,r2,r3,r4) S1C(u2, r2,r3,r4,r5)
            S1C(u3, r3,r4,r5,r6) S1C(u4, r4,r5,r6,r7) S1C(u5, r5,r6,r7,r8)
            S1C(u6, r6,r7,r8,r9)
            LDR(bp + 2*XSTR)
            S1C(u7, q0,q1,q2,q3) S1C(u8, q1,q2,q3,q4) S1C(u9, q2,q3,q4,q5)
            S1C(u10,q3,q4,q5,q6) S1C(u11,q4,q5,q6,q7) S1C(u12,q5,q6,q7,q8)
            S1C(u13,q6,q7,q8,q9)
            LDQ(bp + 3*XSTR)
            S1C(u14,r0,r1,r2,r3) S1C(u15,r1,r2,r3,r4) S1C(u16,r2,r3,r4,r5)
            S1C(u17,r3,r4,r5,r6) S1C(u18,r4,r5,r6,r7) S1C(u19,r5,r6,r7,r8)
            S1C(u20,r6,r7,r8,r9)
            LDR(bp + 4*XSTR)
            S1C(u21,q0,q1,q2,q3) S1C(u22,q1,q2,q3,q4) S1C(u23,q2,q3,q4,q5)
            S1C(u24,q3,q4,q5,q6) S1C(u25,q4,q5,q6,q7) S1C(u26,q5,q6,q7,q8)
            S1C(u27,q6,q7,q8,q9)
            LDQ(bp + 5*XSTR)
            S1C(u28,r0,r1,r2,r3) S1C(u29,r1,r2,r3,r4) S1C(u30,r2,r3,r4,r5)
            S1C(u31,r3,r4,r5,r6) S1C(u32,r4,r5,r6,r7) S1C(u33,r5,r6,r7,r8)
            S1C(u34,r6,r7,r8,r9)
            LDR(bp + 6*XSTR)
            S1C(u35,q0,q1,q2,q3) S1C(u36,q1,q2,q3,q4) S1C(u37,q2,q3,q4,q5)
            S1C(u38,q3,q4,q5,q6) S1C(u39,q4,q5,q6,q7) S1C(u40,q5,q6,q7,q8)
            S1C(u41,q6,q7,q8,q9)
            S1C(u42,r0,r1,r2,r3) S1C(u43,r1,r2,r3,r4) S1C(u44,r2,r3,r4,r5)
            S1C(u45,r3,r4,r5,r6) S1C(u46,r4,r5,r6,r7) S1C(u47,r5,r6,r7,r8)
            S1C(u48,r6,r7,r8,r9)
            const int gm = q16 - 3 + row;
            const bool in_img = (gm >= 0) && (gm < IMG);
            float* mp = &ms[row * XSTR + 3 + cs4];
            mp[0] = in_img ? a0 : 0.f;
            mp[1] = in_img ? a1 : 0.f;
            mp[2] = in_img ? a2 : 0.f;
            mp[3] = in_img ? a3 : 0.f;
        }
    }
    __syncthreads();

    // ---- stage 2 + code bits: 16 rows x 16 col-strips = 256 strips ----
    {
        const int rr  = tid >> 4;             // out row 0..15
        const int cs4 = (tid & 15) * 4;       // pixel col 0..60
        const float* bp = &ms[rr * XSTR + cs4];
        DECLRQ
        float s0 = 0.f, s1 = 0.f, s2 = 0.f, s3 = 0.f;
        SUMPASS(bp)
        const float mu0 = s0 / 49.0f, mu1 = s1 / 49.0f;
        const float mu2 = s2 / 49.0f, mu3 = s3 / 49.0f;
        float a0=0.f,a1=0.f,a2=0.f,a3=0.f,a4=0.f,a5=0.f,a6=0.f,a7=0.f;
        float b0=0.f,b1=0.f,b2=0.f,b3=0.f,b4=0.f,b5=0.f,b6=0.f,b7=0.f;
        float c0=0.f,c1=0.f,c2=0.f,c3=0.f,c4=0.f,c5=0.f,c6=0.f,c7=0.f;
        float d0=0.f,d1=0.f,d2=0.f,d3=0.f,d4=0.f,d5=0.f,d6=0.f,d7=0.f;
        float g0,g1,g2,g3,g4,g5,g6,g7,g8,g9,g10,g11,g12,g13,g14,g15;
        float g16,g17,g18,g19,g20,g21,g22,g23,g24,g25,g26,g27,g28,g29,g30,g31;
        float h0,h1,h2,h3,h4,h5,h6,h7,h8,h9,h10,h11,h12,h13,h14,h15;
        float h16,h17,h18,h19,h20,h21,h22,h23,h24,h25,h26,h27,h28,h29,h30,h31;
        LDR(bp + 0*XSTR) PFG32(g,0) FENCE
        // row0 (r)
        PFG32(h,1) LDQ(bp + 1*XSTR)
        S2C(g0,g1,g2,g3,g4,g5,g6,g7,          r0,r1,r2,r3)
        S2C(g8,g9,g10,g11,g12,g13,g14,g15,    r1,r2,r3,r4)
        S2C(g16,g17,g18,g19,g20,g21,g22,g23,  r2,r3,r4,r5)
        S2C(g24,g25,g26,g27,g28,g29,g30,g31,  r3,r4,r5,r6)
        PFG32(g,2)
        S2C(h0,h1,h2,h3,h4,h5,h6,h7,          r4,r5,r6,r7)
        S2C(h8,h9,h10,h11,h12,h13,h14,h15,    r5,r6,r7,r8)
        S2C(h16,h17,h18,h19,h20,h21,h22,h23,  r6,r7,r8,r9)
        // row1 (q)
        LDR(bp + 2*XSTR)
        S2C(h24,h25,h26,h27,h28,h29,h30,h31,  q0,q1,q2,q3)
        PFG32(h,3)
        S2C(g0,g1,g2,g3,g4,g5,g6,g7,          q1,q2,q3,q4)
        S2C(g8,g9,g10,g11,g12,g13,g14,g15,    q2,q3,q4,q5)
        S2C(g16,g17,g18,g19,g20,g21,g22,g23,  q3,q4,q5,q6)
        S2C(g24,g25,g26,g27,g28,g29,g30,g31,  q4,q5,q6,q7)
        PFG32(g,4)
        S2C(h0,h1,h2,h3,h4,h5,h6,h7,          q5,q6,q7,q8)
        S2C(h8,h9,h10,h11,h12,h13,h14,h15,    q6,q7,q8,q9)
        // row2 (r)
        LDQ(bp + 3*XSTR)
        S2C(h16,h17,h18,h19,h20,h21,h22,h23,  r0,r1,r2,r3)
        S2C(h24,h25,h26,h27,h28,h29,h30,h31,  r1,r2,r3,r4)
        PFG32(h,5)
        S2C(g0,g1,g2,g3,g4,g5,g6,g7,          r2,r3,r4,r5)
        S2C(g8,g9,g10,g11,g12,g13,g14,g15,    r3,r4,r5,r6)
        S2C(g16,g17,g18,g19,g20,g21,g22,g23,  r4,r5,r6,r7)
        S2C(g24,g25,g26,g27,g28,g29,g30,g31,  r5,r6,r7,r8)
        PFG32(g,6)
        S2C(h0,h1,h2,h3,h4,h5,h6,h7,          r6,r7,r8,r9)
        // row3 (q)
        LDR(bp + 4*XSTR)
        S2C(h8,h9,h10,h11,h12,h13,h14,h15,    q0,q1,q2,q3)
        S2C(h16,h17,h18,h19,h20,h21,h22,h23,  q1,q2,q3,q4)
        S2C(h24,h25,h26,h27,h28,h29,h30,h31,  q2,q3,q4,q5)
        PFG32(h,7)
        S2C(g0,g1,g2,g3,g4,g5,g6,g7,          q3,q4,q5,q6)
        S2C(g8,g9,g10,g11,g12,g13,g14,g15,    q4,q5,q6,q7)
        S2C(g16,g17,g18,g19,g20,g21,g22,g23,  q5,q6,q7,q8)
        S2C(g24,g25,g26,g27,g28,g29,g30,g31,  q6,q7,q8,q9)
        // row4 (r)
        PFG32(g,8) LDQ(bp + 5*XSTR)
        S2C(h0,h1,h2,h3,h4,h5,h6,h7,          r0,r1,r2,r3)
        S2C(h8,h9,h10,h11,h12,h13,h14,h15,    r1,r2,r3,r4)
        S2C(h16,h17,h18,h19,h20,h21,h22,h23,  r2,r3,r4,r5)
        S2C(h24,h25,h26,h27,h28,h29,h30,h31,  r3,r4,r5,r6)
        PFG32(h,9)
        S2C(g0,g1,g2,g3,g4,g5,g6,g7,          r4,r5,r6,r7)
        S2C(g8,g9,g10,g11,g12,g13,g14,g15,    r5,r6,r7,r8)
        S2C(g16,g17,g18,g19,g20,g21,g22,g23,  r6,r7,r8,r9)
        // row5 (q)
        LDR(bp + 6*XSTR)
        S2C(g24,g25,g26,g27,g28,g29,g30,g31,  q0,q1,q2,q3)
        PFG32(g,10)
        S2C(h0,h1,h2,h3,h4,h5,h6,h7,          q1,q2,q3,q4)
        S2C(h8,h9,h10,h11,h12,h13,h14,h15,    q2,q3,q4,q5)
        S2C(h16,h17,h18,h19,h20,h21,h22,h23,  q3,q4,q5,q6)
        S2C(h24,h25,h26,h27,h28,h29,h30,h31,  q4,q5,q6,q7)
        PFG32(h,11)
        S2C(g0,g1,g2,g3,g4,g5,g6,g7,          q5,q6,q7,q8)
        S2C(g8,g9,g10,g11,g12,g13,g14,g15,    q6,q7,q8,q9)
        // row6 (r)
        S2C(g16,g17,g18,g19,g20,g21,g22,g23,  r0,r1,r2,r3)
        S2C(g24,g25,g26,g27,g28,g29,g30,g31,  r1,r2,r3,r4)
        PFG8(g,12)
        S2C(h0,h1,h2,h3,h4,h5,h6,h7,          r2,r3,r4,r5)
        S2C(h8,h9,h10,h11,h12,h13,h14,h15,    r3,r4,r5,r6)
        S2C(h16,h17,h18,h19,h20,h21,h22,h23,  r4,r5,r6,r7)
        S2C(h24,h25,h26,h27,h28,h29,h30,h31,  r5,r6,r7,r8)
        S2C(g0,g1,g2,g3,g4,g5,g6,g7,          r6,r7,r8,r9)
        uint32_t k0 = 0, k1 = 0, k2 = 0, k3 = 0;
        k0 |= (a0>0.f)?128u:0u; k1 |= (b0>0.f)?128u:0u; k2 |= (c0>0.f)?128u:0u; k3 |= (d0>0.f)?128u:0u;
        k0 |= (a1>0.f)? 64u:0u; k1 |= (b1>0.f)? 64u:0u; k2 |= (c1>0.f)? 64u:0u; k3 |= (d1>0.f)? 64u:0u;
        k0 |= (a2>0.f)? 32u:0u; k1 |= (b2>0.f)? 32u:0u; k2 |= (c2>0.f)? 32u:0u; k3 |= (d2>0.f)? 32u:0u;
        k0 |= (a3>0.f)? 16u:0u; k1 |= (b3>0.f)? 16u:0u; k2 |= (c3>0.f)? 16u:0u; k3 |= (d3>0.f)? 16u:0u;
        k0 |= (a4>0.f)?  8u:0u; k1 |= (b4>0.f)?  8u:0u; k2 |= (c4>0.f)?  8u:0u; k3 |= (d4>0.f)?  8u:0u;
        k0 |= (a5>0.f)?  4u:0u; k1 |= (b5>0.f)?  4u:0u; k2 |= (c5>0.f)?  4u:0u; k3 |= (d5>0.f)?  4u:0u;
        k0 |= (a6>0.f)?  2u:0u; k1 |= (b6>0.f)?  2u:0u; k2 |= (c6>0.f)?  2u:0u; k3 |= (d6>0.f)?  2u:0u;
        k0 |= (a7>0.f)?  1u:0u; k1 |= (b7>0.f)?  1u:0u; k2 |= (c7>0.f)?  1u:0u; k3 |= (d7>0.f)?  1u:0u;
        uint32_t packed = k0 | (k1 << 8) | (k2 << 16) | (k3 << 24);
        *(uint32_t*)(codes + (size_t)ch * PIX + (q16 + rr) * 64 + cs4) = packed;
    }
}

// ---------------------------------------------------------------------------
// Kernel B: histogram + entropy (unchanged, ~4 us)
// ---------------------------------------------------------------------------
#define CPB 32

__global__ __launch_bounds__(256) void hist_kernel(
    const uint8_t* __restrict__ codes,  // [512][4096]
    float* __restrict__ out)            // [49*256][512]
{
    __shared__ uint32_t hist[256 * 33];

    const int bid   = blockIdx.x;       // 0..783
    const int cgrp  = bid & 15;
    const int nb    = bid >> 4;         // 0..48
    const int bi    = nb / 7, bj = nb - bi * 7;
    const int tid   = threadIdx.x;
    const int cbase = cgrp * CPB;

    for (int i = tid; i < 256 * 33; i += 256) hist[i] = 0;
    __syncthreads();

    const int cl  = tid >> 3;           // 0..31
    const int sub = tid & 7;            // 0..7
    const uint8_t* cp = codes + (size_t)(cbase + cl) * PIX;
    #pragma unroll
    for (int rr = 0; rr < 2; ++rr) {
        int row = bi * 8 + (sub * 2 + rr);
        const uint8_t* rp = cp + row * 64 + bj * 8;
        uint64_t v0 = *(const uint64_t*)(rp);
        uint64_t v1 = *(const uint64_t*)(rp + 8);
        #pragma unroll
        for (int t = 0; t < 8; ++t)
            atomicAdd(&hist[(uint32_t)((v0 >> (8 * t)) & 255u) * 33 + cl], 1u);
        #pragma unroll
        for (int t = 0; t < 8; ++t)
            atomicAdd(&hist[(uint32_t)((v1 >> (8 * t)) & 255u) * 33 + cl], 1u);
    }
    __syncthreads();

    const int lane_c = tid & 31;
    const int bin0   = tid >> 5;        // 0..7
    for (int i = 0; i < 32; ++i) {
        int bin = i * 8 + bin0;
        uint32_t cnt = hist[bin * 33 + lane_c];
        float ent = 0.f;
        if (cnt > 0) {
            float pz = (float)cnt * (1.0f / 256.0f);
            ent = -pz * log2f(pz);
        }
        out[((size_t)(nb * 256 + bin)) * 512 + cbase + lane_c] = ent;
    }
}

extern "C" void kernel_launch(void* const* d_in, const int* in_sizes, int n_in,
                              void* d_out, int out_size, void* d_ws, size_t ws_size,
                              hipStream_t stream) {
    const float* x  = (const float*)d_in[0];
    const float* W1 = (const float*)d_in[1];
    const float* W2 = (const float*)d_in[2];
    float* out = (float*)d_out;
    uint8_t* codes = (uint8_t*)d_ws;   // 512*4096 = 2 MB

    stage_kernel<<<2048, 256, 0, stream>>>(x, W1, W2, codes);
    hist_kernel<<<784, 256, 0, stream>>>(codes, out);
}